// Round 13
// baseline (46.083 us; speedup 1.0000x reference)
//
#include <hip/hip_runtime.h>

#define BATCH  8
#define NPTS   16384
#define LVOX   605     // 11*11*5 = 121 xy-columns * 5 z
#define ABINS  8
#define CH     23
#define NCOL   121
#define NBIN   14      // floor(d) <= 13 (max dist 13.89); feature[14] == 1.0
#define BPTS   256     // points per feature block
#define FEAT_BLOCKS (BATCH * (NPTS / BPTS))   // 512
#define ROT_CH    4
#define ROT_CHPTS (NPTS / ROT_CH)             // 4096
#define ROT_BLOCKS (ABINS * BATCH * ROT_CH)   // 256

#define ROT_WS_U32  (ABINS * BATCH * LVOX)          // 38720
#define FEAT_WS_U32 (BATCH * LVOX * (NBIN / 2))     // 8*605*7 = 33880 (u16 pairs)
#define WS_U32_TOTAL (ROT_WS_U32 + FEAT_WS_U32)     // 72600  (~290 KB)

// ---------------------------------------------------------------------------
// Workspace zeroing — own kernel, no hipMemsetAsync.
// ---------------------------------------------------------------------------
__global__ __launch_bounds__(256) void zero_kernel(unsigned* __restrict__ ws) {
    const int i = blockIdx.x * 256 + threadIdx.x;
    if (i < WS_U32_TOTAL) ws[i] = 0u;
}

// ---------------------------------------------------------------------------
// Fused kernel, 512 threads.
// R13: sqrt eliminated.  bin = floor(sqrt(d2)) == floor(sqrt(floor(d2)))
// exactly (bin boundaries k^2 are integers), so bin comes from a 194-entry
// LDS LUT indexed by (int)d2.  LUT stores PRE-SHIFTED byte offsets k*512
// (= hist row stride), replicated 4x at 200-word stride so the 4 copies hit
// bank groups offset by 8 (damps data-dependent conflicts).  Inner loop per
// point-z: fma, cvt, lshl_add, ds_read_b32, v_add, ds_add — zero trans pipe.
// Blocks [0,512): features.  Blocks [512,768): rot histogram (unchanged).
// ---------------------------------------------------------------------------
__global__ __launch_bounds__(512) void main_kernel(const float* __restrict__ pcd,
                                                   int* __restrict__ rot_hist,
                                                   unsigned* __restrict__ feat_hist) {
    __shared__ unsigned hist[5][NBIN][128];   // 35840 B  (row stride 512 B)
    __shared__ unsigned lut[4][200];          //  3200 B  (194 used per copy)
    __shared__ float4  pts[BPTS];             //  4096 B
    const int bid = blockIdx.x;
    const int tid = threadIdx.x;

    if (bid < FEAT_BLOCKS) {
        const int b     = bid >> 6;      // /64
        const int outer = bid & 63;

        // ---- stage points, zero hist, fill LUT ----
        {
            const float* __restrict__ src = pcd + ((size_t)b * NPTS + outer * BPTS) * 3;
            float* pf = (float*)pts;
            for (int i = tid; i < BPTS * 3; i += 512) pf[(i / 3) * 4 + (i % 3)] = src[i];
            unsigned* hp = &hist[0][0][0];
            for (int i = tid; i < 5 * NBIN * 128; i += 512) hp[i] = 0u;
            if (tid < 194) {
                const unsigned k = (unsigned)__builtin_amdgcn_sqrtf((float)tid);
                const unsigned v = k << 9;           // k * 512 bytes
#pragma unroll
                for (int c = 0; c < 4; ++c) lut[c][tid] = v;
            }
        }
        __syncthreads();

        const int li = tid & 127;                     // histogram column
        const int cc = (li < NCOL) ? li : (NCOL - 1); // clamp so k <= 13
        const float lx = -5.0f + (float)(cc / 11);
        const float ly = -5.0f + (float)(cc % 11);
        const int pbase = (tid >> 7) * 64;            // wave-pair point quarter

        const unsigned* __restrict__ lrow = &lut[li & 3][0];
        char* const hbase = (char*)&hist[0][0][li];   // + z*7168 + k*512 later

#pragma unroll 4
        for (int j = 0; j < 64; ++j) {
            const float4 P = pts[pbase + j];
            const float dx = P.x - lx, dy = P.y - ly;
            const float rxy2 = fmaf(dy, dy, dx * dx);
            const float dz0 = P.z + 2.0f;
#pragma unroll
            for (int z = 0; z < 5; ++z) {
                const float dz = dz0 - (float)z;
                const float d2 = fmaf(dz, dz, rxy2);
                const unsigned i = (unsigned)d2;            // floor(d2), 0..192
                const unsigned kb = lrow[i];                // k*512 (byte offset)
                atomicAdd((unsigned*)(hbase + (z * 7168 + (size_t)kb)), 1u);
            }
        }
        __syncthreads();

        // ---- epilogue: pack bin pairs (u16|u16), one global atomic each ----
        for (int item = tid; item < NCOL * 5 * (NBIN / 2); item += 512) {
            const int kp  = item % 7;
            const int rem = item / 7;
            const int z   = rem % 5;
            const int col = rem / 5;
            const unsigned v = hist[z][2 * kp][col] | (hist[z][2 * kp + 1][col] << 16);
            if (v) atomicAdd(&feat_hist[((size_t)b * LVOX + col * 5 + z) * 7 + kp], v);
        }
    } else {
        // ------------------ rotation-voxel histogram ------------------
        const int rb    = bid - FEAT_BLOCKS;
        const int ab    = rb & 63;        // a*8 + b
        const int chunk = rb >> 6;        // 0..3
        const int a     = ab >> 3;
        const int b     = ab & 7;

        int* h = (int*)&hist[0][0][0];
        for (int i = tid; i < LVOX; i += 512) h[i] = 0;
        __syncthreads();

        const float C[8] = { -4.3711388e-08f, 0.3826834323650898f, 0.7071067811865476f,
                             0.9238795325112867f, 1.0f, 0.9238795325112867f,
                             0.7071067811865476f, 0.3826834323650898f };
        const float S[8] = { -1.0f, -0.9238795325112867f, -0.7071067811865476f,
                             -0.3826834323650898f, 0.0f, 0.3826834323650898f,
                             0.7071067811865476f, 0.9238795325112867f };
        const float c = C[a];
        const float s = S[a];

        const float* __restrict__ p =
            pcd + ((size_t)b * NPTS + (size_t)chunk * ROT_CHPTS) * 3;

        for (int n = tid; n < ROT_CHPTS; n += 512) {
            const float x = p[n * 3 + 0];
            const float y = p[n * 3 + 1];
            const float z = p[n * 3 + 2];
            const float rx = x * c - y * s + 5.5f;
            const float ry = x * s + y * c + 5.5f;
            const float rz = z + 2.5f;
            const int icx = (int)floorf(rx);
            const int icy = (int)floorf(ry);
            const int icz = (int)floorf(rz);
            const int flat = icz + icy * 5 + icx * 55;
            if (flat >= 0 && flat < LVOX) atomicAdd(&h[flat], 1);
        }
        __syncthreads();

        int* __restrict__ dst = rot_hist + (size_t)ab * LVOX;
        for (int i = tid; i < LVOX; i += 512) {
            const int v = h[i];
            if (v) atomicAdd(&dst[i], v);
        }
    }
}

// ---------------------------------------------------------------------------
// Finalize.  16-lane groups per (b,l): lane q<14 loads its u16 bin count,
// inclusive prefix-scan -> cumulative feature; feature[14] == 1.0 exactly.
// Lanes 0..7 also write the 8 rot channels.
// ---------------------------------------------------------------------------
__global__ __launch_bounds__(256) void write_kernel(const int* __restrict__ rot_hist,
                                                    const unsigned* __restrict__ feat16,
                                                    float* __restrict__ out) {
    const int gt    = blockIdx.x * 256 + threadIdx.x;
    const int group = gt >> 4;                 // (b,l)
    const int q     = gt & 15;
    if (group >= BATCH * LVOX) return;
    const int b = group / LVOX;
    const int l = group % LVOX;

    int v = 0;
    if (q < NBIN) {
        const unsigned w = feat16[(size_t)group * 7 + (q >> 1)];
        v = (int)((w >> (16 * (q & 1))) & 0xFFFFu);
    }
#pragma unroll
    for (int off = 1; off < 16; off <<= 1) {
        const int t = __shfl_up(v, off, 16);
        if (q >= off) v += t;
    }
    const float inv_n = 1.0f / (float)NPTS;
    float* __restrict__ o = out + (size_t)group * CH;
    if (q < NBIN)       o[q]  = (float)v * inv_n;
    else if (q == NBIN) o[14] = 1.0f;
    if (q < 8) {
        const int r = rot_hist[((size_t)q * BATCH + b) * LVOX + l];
        o[15 + q] = (float)r * inv_n;
    }
}

extern "C" void kernel_launch(void* const* d_in, const int* in_sizes, int n_in,
                              void* d_out, int out_size, void* d_ws, size_t ws_size,
                              hipStream_t stream) {
    const float* pcd = (const float*)d_in[0];
    float* out = (float*)d_out;
    int* rot_hist = (int*)d_ws;
    unsigned* feat16 = (unsigned*)d_ws + ROT_WS_U32;

    hipLaunchKernelGGL(zero_kernel, dim3((WS_U32_TOTAL + 255) / 256), dim3(256), 0,
                       stream, (unsigned*)d_ws);
    hipLaunchKernelGGL(main_kernel, dim3(FEAT_BLOCKS + ROT_BLOCKS), dim3(512), 0,
                       stream, pcd, rot_hist, feat16);
    hipLaunchKernelGGL(write_kernel, dim3((BATCH * LVOX * 16 + 255) / 256), dim3(256),
                       0, stream, rot_hist, feat16, out);
}

// Round 14
// 35.609 us; speedup vs baseline: 1.2942x; 1.2942x over previous
//
#include <hip/hip_runtime.h>

#define BATCH  8
#define NPTS   16384
#define LVOX   605     // 11*11*5 = 121 xy-columns * 5 z
#define ABINS  8
#define CH     23
#define NCOL   121
#define NBIN   14      // floor(d) <= 13 (max dist 13.89); feature[14] == 1.0
#define BPTS   256     // points per feature block
#define FEAT_BLOCKS (BATCH * (NPTS / BPTS))   // 512
#define ROT_CH    4
#define ROT_CHPTS (NPTS / ROT_CH)             // 4096
#define ROT_BLOCKS (ABINS * BATCH * ROT_CH)   // 256

#define ROT_WS_U32  (ABINS * BATCH * LVOX)          // 38720
#define FEAT_WS_U32 (BATCH * LVOX * (NBIN / 2))     // 8*605*7 = 33880 (u16 pairs)
#define WS_U32_TOTAL (ROT_WS_U32 + FEAT_WS_U32)     // 72600  (~290 KB)

// ---------------------------------------------------------------------------
// Workspace zeroing — own kernel, no hipMemsetAsync.
// ---------------------------------------------------------------------------
__global__ __launch_bounds__(256) void zero_kernel(unsigned* __restrict__ ws) {
    const int i = blockIdx.x * 256 + threadIdx.x;
    if (i < WS_U32_TOTAL) ws[i] = 0u;
}

// ---------------------------------------------------------------------------
// Fused kernel, 512 threads = R12 structure (best: 37.2us) minus the LDS
// point-broadcast: R13 proved the LDS pipe is the binding resource (+1.31M
// LDS reads cost +9us), so points now come from WAVE-UNIFORM global reads
// (readfirstlane-proven pointer + literal unrolled offsets -> s_load on the
// SMEM pipe).  LDS traffic is now just the irreducible 1 ds_add_u32 per
// point-z into the conflict-free hist[z][k][column] (lane=column).
// Blocks [0,512): features.  Blocks [512,768): rot histogram (unchanged).
// ---------------------------------------------------------------------------
__global__ __launch_bounds__(512) void main_kernel(const float* __restrict__ pcd,
                                                   int* __restrict__ rot_hist,
                                                   unsigned* __restrict__ feat_hist) {
    __shared__ unsigned hist[5][NBIN][128];   // 35840 B (row stride 512 B)
    const int bid = blockIdx.x;
    const int tid = threadIdx.x;

    if (bid < FEAT_BLOCKS) {
        const int b     = bid >> 6;      // /64
        const int outer = bid & 63;

        // ---- zero hist ----
        {
            unsigned* hp = &hist[0][0][0];
            for (int i = tid; i < 5 * NBIN * 128; i += 512) hp[i] = 0u;
        }

        const int li = tid & 127;                     // histogram column
        const int cc = (li < NCOL) ? li : (NCOL - 1); // clamp so k <= 13
        const float lx = -5.0f + (float)(cc / 11);
        const float ly = -5.0f + (float)(cc % 11);
        // wave-uniform point quarter; readfirstlane proves uniformity so the
        // point loads scalarize to s_load (SMEM pipe, off the LDS pipe).
        const int pbase = __builtin_amdgcn_readfirstlane(tid >> 7) * 64;
        const float* __restrict__ pp =
            pcd + ((size_t)b * NPTS + outer * BPTS + pbase) * 3;

        __syncthreads();

#pragma unroll 4
        for (int j = 0; j < 64; ++j) {
            const float px = pp[j * 3 + 0];
            const float py = pp[j * 3 + 1];
            const float pz = pp[j * 3 + 2];
            const float dx = px - lx, dy = py - ly;
            const float rxy2 = fmaf(dy, dy, dx * dx);
            const float dz0 = pz + 2.0f;
#pragma unroll
            for (int z = 0; z < 5; ++z) {
                const float dz = dz0 - (float)z;
                const float d  = __builtin_amdgcn_sqrtf(fmaf(dz, dz, rxy2));
                const int   k  = (int)d;             // floor(d) == ceil(d)-1 a.e.
                atomicAdd(&hist[z][k][li], 1u);      // ds_add_u32, conflict-free
            }
        }
        __syncthreads();

        // ---- epilogue: pack bin pairs (u16|u16), one global atomic each ----
        for (int item = tid; item < NCOL * 5 * (NBIN / 2); item += 512) {
            const int kp  = item % 7;
            const int rem = item / 7;
            const int z   = rem % 5;
            const int col = rem / 5;
            const unsigned v = hist[z][2 * kp][col] | (hist[z][2 * kp + 1][col] << 16);
            if (v) atomicAdd(&feat_hist[((size_t)b * LVOX + col * 5 + z) * 7 + kp], v);
        }
    } else {
        // ------------------ rotation-voxel histogram ------------------
        const int rb    = bid - FEAT_BLOCKS;
        const int ab    = rb & 63;        // a*8 + b
        const int chunk = rb >> 6;        // 0..3
        const int a     = ab >> 3;
        const int b     = ab & 7;

        int* h = (int*)&hist[0][0][0];
        for (int i = tid; i < LVOX; i += 512) h[i] = 0;
        __syncthreads();

        const float C[8] = { -4.3711388e-08f, 0.3826834323650898f, 0.7071067811865476f,
                             0.9238795325112867f, 1.0f, 0.9238795325112867f,
                             0.7071067811865476f, 0.3826834323650898f };
        const float S[8] = { -1.0f, -0.9238795325112867f, -0.7071067811865476f,
                             -0.3826834323650898f, 0.0f, 0.3826834323650898f,
                             0.7071067811865476f, 0.9238795325112867f };
        const float c = C[a];
        const float s = S[a];

        const float* __restrict__ p =
            pcd + ((size_t)b * NPTS + (size_t)chunk * ROT_CHPTS) * 3;

        for (int n = tid; n < ROT_CHPTS; n += 512) {
            const float x = p[n * 3 + 0];
            const float y = p[n * 3 + 1];
            const float z = p[n * 3 + 2];
            const float rx = x * c - y * s + 5.5f;
            const float ry = x * s + y * c + 5.5f;
            const float rz = z + 2.5f;
            const int icx = (int)floorf(rx);
            const int icy = (int)floorf(ry);
            const int icz = (int)floorf(rz);
            const int flat = icz + icy * 5 + icx * 55;
            if (flat >= 0 && flat < LVOX) atomicAdd(&h[flat], 1);
        }
        __syncthreads();

        int* __restrict__ dst = rot_hist + (size_t)ab * LVOX;
        for (int i = tid; i < LVOX; i += 512) {
            const int v = h[i];
            if (v) atomicAdd(&dst[i], v);
        }
    }
}

// ---------------------------------------------------------------------------
// Finalize.  16-lane groups per (b,l): lane q<14 loads its u16 bin count,
// inclusive prefix-scan -> cumulative feature; feature[14] == 1.0 exactly.
// Lanes 0..7 also write the 8 rot channels.
// ---------------------------------------------------------------------------
__global__ __launch_bounds__(256) void write_kernel(const int* __restrict__ rot_hist,
                                                    const unsigned* __restrict__ feat16,
                                                    float* __restrict__ out) {
    const int gt    = blockIdx.x * 256 + threadIdx.x;
    const int group = gt >> 4;                 // (b,l)
    const int q     = gt & 15;
    if (group >= BATCH * LVOX) return;
    const int b = group / LVOX;
    const int l = group % LVOX;

    int v = 0;
    if (q < NBIN) {
        const unsigned w = feat16[(size_t)group * 7 + (q >> 1)];
        v = (int)((w >> (16 * (q & 1))) & 0xFFFFu);
    }
#pragma unroll
    for (int off = 1; off < 16; off <<= 1) {
        const int t = __shfl_up(v, off, 16);
        if (q >= off) v += t;
    }
    const float inv_n = 1.0f / (float)NPTS;
    float* __restrict__ o = out + (size_t)group * CH;
    if (q < NBIN)       o[q]  = (float)v * inv_n;
    else if (q == NBIN) o[14] = 1.0f;
    if (q < 8) {
        const int r = rot_hist[((size_t)q * BATCH + b) * LVOX + l];
        o[15 + q] = (float)r * inv_n;
    }
}

extern "C" void kernel_launch(void* const* d_in, const int* in_sizes, int n_in,
                              void* d_out, int out_size, void* d_ws, size_t ws_size,
                              hipStream_t stream) {
    const float* pcd = (const float*)d_in[0];
    float* out = (float*)d_out;
    int* rot_hist = (int*)d_ws;
    unsigned* feat16 = (unsigned*)d_ws + ROT_WS_U32;

    hipLaunchKernelGGL(zero_kernel, dim3((WS_U32_TOTAL + 255) / 256), dim3(256), 0,
                       stream, (unsigned*)d_ws);
    hipLaunchKernelGGL(main_kernel, dim3(FEAT_BLOCKS + ROT_BLOCKS), dim3(512), 0,
                       stream, pcd, rot_hist, feat16);
    hipLaunchKernelGGL(write_kernel, dim3((BATCH * LVOX * 16 + 255) / 256), dim3(256),
                       0, stream, rot_hist, feat16, out);
}